// Round 1
// baseline (2507.155 us; speedup 1.0000x reference)
//
#include <hip/hip_runtime.h>
#include <hip/hip_bf16.h>
#include <cstdint>
#include <cstddef>

// Problem constants: B=16, S=128, IN=200, H=256, 4H=1024, 2H=512

__device__ __forceinline__ float bf2f(unsigned short u) {
    return __uint_as_float(((unsigned)u) << 16);
}

// ---------------- prep kernels ----------------

// dst[z][k][n] = src[z][n][k], n<1024 (rows of src), k<K
__global__ void k_transpose_N1024(const float* __restrict__ src, float* __restrict__ dst, int K) {
    int z = blockIdx.z;
    int idx = blockIdx.x * 256 + threadIdx.x;
    if (idx >= K * 1024) return;
    int k = idx >> 10, n = idx & 1023;
    dst[(size_t)z * K * 1024 + idx] = src[(size_t)z * 1024 * K + (size_t)n * K + k];
}

// src (2,1024,256) fp32 -> dst[z][k=256][r=1024] bf16 (RNE)
__global__ void k_whh_bf16(const float* __restrict__ src, unsigned short* __restrict__ dst) {
    int z = blockIdx.z;
    int idx = blockIdx.x * 256 + threadIdx.x;
    if (idx >= 256 * 1024) return;
    int k = idx >> 10, r = idx & 1023;
    float v = src[(size_t)z * (1024 * 256) + (size_t)r * 256 + k];
    unsigned u = __float_as_uint(v);
    u = (u + 0x7FFFu + ((u >> 16) & 1u)) >> 16;
    dst[(size_t)z * (256 * 1024) + idx] = (unsigned short)u;
}

// W1 (256,1024) -> dst[k][o], k<512, o<512 ; o<256: W1[o][k], else W1[o-256][512+k]
__global__ void k_w1t(const float* __restrict__ W1, float* __restrict__ dst) {
    int idx = blockIdx.x * 256 + threadIdx.x;
    if (idx >= 512 * 512) return;
    int k = idx >> 9, o = idx & 511;
    dst[idx] = (o < 256) ? W1[(size_t)o * 1024 + k] : W1[(size_t)(o - 256) * 1024 + 512 + k];
}

__global__ void k_bias(const float* __restrict__ bih0, const float* __restrict__ bhh0,
                       const float* __restrict__ bih1, const float* __restrict__ bhh1,
                       const float* __restrict__ b1,
                       float* __restrict__ bsum0, float* __restrict__ bsum1, float* __restrict__ bhab) {
    int idx = blockIdx.x * 256 + threadIdx.x;
    if (idx < 2048) bsum0[idx] = bih0[idx] + bhh0[idx];
    else if (idx < 4096) { int i = idx - 2048; bsum1[i] = bih1[i] + bhh1[i]; }
    else if (idx < 4608) { int i = idx - 4096; bhab[i] = (i < 256) ? b1[i] : 0.f; }
}

// ---------------- generic GEMM: out[z][m][n] = bias[z][n] + sum_k A[m][k]*Wt[z][k][n] ----------------
// block: 256 thr, tile 16m x 256n. grid (N/256, M/16, Z). A row-major stride K (shared by all z).
__global__ __launch_bounds__(256) void k_gemm(
    const float* __restrict__ A, const float* __restrict__ Wt,
    const float* __restrict__ bias, float* __restrict__ out,
    int M, int K, int N)
{
    int z = blockIdx.z;
    const float* Wtz = Wt + (size_t)z * K * N;
    float* outz = out + (size_t)z * M * N;
    const float* biasz = bias + (size_t)z * N;

    __shared__ float As[16 * 512];
    int tid = threadIdx.x;
    int mq = tid >> 6;       // 0..3 (one wave per mq)
    int nq = tid & 63;       // 0..63
    int n0 = blockIdx.x * 256 + nq * 4;
    int mbase = blockIdx.y * 16;

    for (int r = 0; r < 16; ++r) {
        const float* Ar = A + (size_t)(mbase + r) * K;
        for (int c = tid; c < K; c += 256) As[r * K + c] = Ar[c];
    }
    __syncthreads();

    float4 bv = *(const float4*)(biasz + n0);
    float acc[4][4];
#pragma unroll
    for (int mi = 0; mi < 4; mi++) { acc[mi][0] = bv.x; acc[mi][1] = bv.y; acc[mi][2] = bv.z; acc[mi][3] = bv.w; }

    const float* asr = As + (mq * 4) * K;
    for (int k = 0; k < K; ++k) {
        float4 w = *(const float4*)(Wtz + (size_t)k * N + n0);
        float x0 = asr[k];
        float x1 = asr[K + k];
        float x2 = asr[2 * K + k];
        float x3 = asr[3 * K + k];
        acc[0][0] += x0 * w.x; acc[0][1] += x0 * w.y; acc[0][2] += x0 * w.z; acc[0][3] += x0 * w.w;
        acc[1][0] += x1 * w.x; acc[1][1] += x1 * w.y; acc[1][2] += x1 * w.z; acc[1][3] += x1 * w.w;
        acc[2][0] += x2 * w.x; acc[2][1] += x2 * w.y; acc[2][2] += x2 * w.z; acc[2][3] += x2 * w.w;
        acc[3][0] += x3 * w.x; acc[3][1] += x3 * w.y; acc[3][2] += x3 * w.z; acc[3][3] += x3 * w.w;
    }
#pragma unroll
    for (int mi = 0; mi < 4; mi++) {
        size_t m = (size_t)mbase + mq * 4 + mi;
        *(float4*)(outz + m * N + n0) = make_float4(acc[mi][0], acc[mi][1], acc[mi][2], acc[mi][3]);
    }
}

// ---------------- LSTM recurrence: one block per (dir,batch) chain ----------------
// xg   [2][2048][1024] (row m = b*128+t), WhhT [2][256][1024] bf16, emb [2048][512]
__global__ __launch_bounds__(512) void k_lstm(
    const float* __restrict__ xg, const unsigned short* __restrict__ WhhT,
    float* __restrict__ emb)
{
    int bz = blockIdx.x;     // 0..31
    int d = bz >> 4;
    int b = bz & 15;
    int tid = threadIdx.x;
    int kh = tid >> 8;       // k-half 0/1
    int u = tid & 255;
    int g = u >> 6;          // gate 0..3 (i,f,g,o)
    int c0 = (u & 63) * 4;
    int r0 = g * 256 + c0;   // gate-row base (4 consecutive rows)

    __shared__ __align__(16) float hs[256];
    __shared__ __align__(16) float gpart[2048];

    float c_state = 0.f;
    if (tid < 256) hs[tid] = 0.f;
    __syncthreads();

    const unsigned short* Wd = WhhT + (size_t)d * (256 * 1024) + (size_t)(kh * 128) * 1024 + r0;
    const float* xgd = xg + (size_t)d * (2048 * 1024) + (size_t)b * (128 * 1024) + r0;
    float* embp = emb + d * 256;

    for (int s = 0; s < 128; ++s) {
        int t = d ? (127 - s) : s;
        float a0 = 0.f, a1 = 0.f, a2 = 0.f, a3 = 0.f;
        if (kh == 0) {
            float4 xv = *(const float4*)(xgd + (size_t)t * 1024);
            a0 = xv.x; a1 = xv.y; a2 = xv.z; a3 = xv.w;
        }
        const float* hp = hs + kh * 128;
        const unsigned short* wp = Wd;
#pragma unroll 2
        for (int k = 0; k < 128; k += 4) {
            float4 hv = *(const float4*)(hp + k);
            ushort4 w0 = *(const ushort4*)(wp);
            ushort4 w1 = *(const ushort4*)(wp + 1024);
            ushort4 w2 = *(const ushort4*)(wp + 2048);
            ushort4 w3 = *(const ushort4*)(wp + 3072);
            wp += 4096;
            a0 += hv.x * bf2f(w0.x); a1 += hv.x * bf2f(w0.y); a2 += hv.x * bf2f(w0.z); a3 += hv.x * bf2f(w0.w);
            a0 += hv.y * bf2f(w1.x); a1 += hv.y * bf2f(w1.y); a2 += hv.y * bf2f(w1.z); a3 += hv.y * bf2f(w1.w);
            a0 += hv.z * bf2f(w2.x); a1 += hv.z * bf2f(w2.y); a2 += hv.z * bf2f(w2.z); a3 += hv.z * bf2f(w2.w);
            a0 += hv.w * bf2f(w3.x); a1 += hv.w * bf2f(w3.y); a2 += hv.w * bf2f(w3.z); a3 += hv.w * bf2f(w3.w);
        }
        *(float4*)(gpart + kh * 1024 + r0) = make_float4(a0, a1, a2, a3);
        __syncthreads();
        if (tid < 256) {
            int j = tid;
            float ig = gpart[j] + gpart[1024 + j];
            float fg = gpart[256 + j] + gpart[1280 + j];
            float gg = gpart[512 + j] + gpart[1536 + j];
            float og = gpart[768 + j] + gpart[1792 + j];
            float si = 1.f / (1.f + __expf(-ig));
            float sf = 1.f / (1.f + __expf(-fg));
            float so = 1.f / (1.f + __expf(-og));
            float e2g = __expf(2.f * gg);
            float tg = (e2g - 1.f) / (e2g + 1.f);
            c_state = sf * c_state + si * tg;
            float e2c = __expf(2.f * c_state);
            float tc = (e2c - 1.f) / (e2c + 1.f);
            float h = so * tc;
            hs[j] = h;
            embp[(size_t)(b * 128 + t) * 512 + j] = h;
        }
        __syncthreads();
    }
}

// ---------------- fused pairwise scorer ----------------
// HaHb [2048][512] ([0:256]=Ha+b1, [256:512]=Hb); W2 (128,256); score (16,128,128)
__global__ __launch_bounds__(256) void k_scorer(
    const float* __restrict__ HaHb, const float* __restrict__ W2,
    const float* __restrict__ b2, const float* __restrict__ W3,
    const float* __restrict__ b3v, float* __restrict__ score)
{
    int jt = blockIdx.x;   // 0..3 (j tile of 32)
    int i  = blockIdx.y;   // 0..127
    int b  = blockIdx.z;   // 0..15
    int tid = threadIdx.x;

    __shared__ __align__(16) float ha[256];
    __shared__ __align__(16) float h1[32 * 260];
    __shared__ __align__(16) float w2s[128 * 36];

    ha[tid] = HaHb[(size_t)(b * 128 + i) * 512 + tid];
    __syncthreads();

    {
        int j = tid >> 3;
        int q = tid & 7;
        const float* hbrow = HaHb + (size_t)(b * 128 + jt * 32 + j) * 512 + 256;
        float* h1r = h1 + j * 260;
#pragma unroll
        for (int cc = 0; cc < 32; ++cc) {
            int c = q + cc * 8;
            float v = ha[c] + hbrow[c];
            h1r[c] = v > 0.f ? v : 0.f;
        }
    }

    float acc[4][4] = {};
    int jq = tid >> 5;   // 0..7 -> j = jq + jj*8
    int rq = tid & 31;   // 0..31 -> r = rq + rr*32

    for (int ch = 0; ch < 8; ++ch) {
        int cb = ch * 32;
        __syncthreads();
        for (int idx = tid; idx < 128 * 32; idx += 256) {
            int r = idx >> 5, cc = idx & 31;
            w2s[r * 36 + cc] = W2[(size_t)r * 256 + cb + cc];
        }
        __syncthreads();
#pragma unroll
        for (int cc = 0; cc < 32; cc += 4) {
            float4 hv[4], wv[4];
#pragma unroll
            for (int jj = 0; jj < 4; ++jj)
                hv[jj] = *(const float4*)(h1 + (jq + jj * 8) * 260 + cb + cc);
#pragma unroll
            for (int rr = 0; rr < 4; ++rr)
                wv[rr] = *(const float4*)(w2s + (rq + rr * 32) * 36 + cc);
#pragma unroll
            for (int jj = 0; jj < 4; ++jj)
#pragma unroll
                for (int rr = 0; rr < 4; ++rr)
                    acc[jj][rr] += hv[jj].x * wv[rr].x + hv[jj].y * wv[rr].y +
                                   hv[jj].z * wv[rr].z + hv[jj].w * wv[rr].w;
        }
    }

    float part0 = 0.f, part1 = 0.f, part2 = 0.f, part3 = 0.f;
#pragma unroll
    for (int rr = 0; rr < 4; ++rr) {
        int r = rq + rr * 32;
        float bb = b2[r], ww = W3[r];
        float t0 = acc[0][rr] + bb; if (t0 > 0.f) part0 += t0 * ww;
        float t1 = acc[1][rr] + bb; if (t1 > 0.f) part1 += t1 * ww;
        float t2 = acc[2][rr] + bb; if (t2 > 0.f) part2 += t2 * ww;
        float t3 = acc[3][rr] + bb; if (t3 > 0.f) part3 += t3 * ww;
    }
#pragma unroll
    for (int off = 16; off >= 1; off >>= 1) {
        part0 += __shfl_xor(part0, off, 32);
        part1 += __shfl_xor(part1, off, 32);
        part2 += __shfl_xor(part2, off, 32);
        part3 += __shfl_xor(part3, off, 32);
    }
    if (rq == 0) {
        float bb3 = b3v[0];
        float p[4] = {part0, part1, part2, part3};
#pragma unroll
        for (int jj = 0; jj < 4; ++jj) {
            int jg = jt * 32 + jq + jj * 8;
            float sc = p[jj] + bb3;
            sc = sc > 0.f ? sc : 0.f;
            if (jg == i || jg == 0) sc = 0.f;
            score[(size_t)(b * 128 + i) * 128 + jg] = sc;
        }
    }
}

// ---------------- loss ----------------
__global__ __launch_bounds__(128) void k_loss1(
    const float* __restrict__ score, const int* __restrict__ tree, float* __restrict__ res)
{
    int k = blockIdx.x;   // 0..126
    int b = blockIdx.y;   // 0..15
    int head = tree[((size_t)b * 128 + k + 1) * 2 + 0];
    int dep  = tree[((size_t)b * 128 + k + 1) * 2 + 1];
    int i = threadIdx.x;  // 0..127
    float s = score[((size_t)b * 128 + i) * 128 + dep];
    float v = (i == dep) ? 0.f : __expf(s);
    __shared__ float redu[2];
#pragma unroll
    for (int off = 32; off >= 1; off >>= 1) v += __shfl_down(v, off, 64);
    if ((i & 63) == 0) redu[i >> 6] = v;
    __syncthreads();
    if (i == 0) {
        float norm = redu[0] + redu[1];
        float num = score[((size_t)b * 128 + head) * 128 + dep];
        res[b * 127 + k] = __logf(norm) - num;
    }
}

__global__ __launch_bounds__(256) void k_loss2(const float* __restrict__ res, float* __restrict__ out) {
    int tid = threadIdx.x;
    float a = 0.f;
    for (int idx = tid; idx < 16 * 127; idx += 256) a += res[idx];
    __shared__ float sm[256];
    sm[tid] = a;
    __syncthreads();
    for (int off = 128; off >= 1; off >>= 1) {
        if (tid < off) sm[tid] += sm[tid + off];
        __syncthreads();
    }
    if (tid == 0) out[0] = sm[0] / 127.f;
}

// ---------------- host launcher ----------------
extern "C" void kernel_launch(void* const* d_in, const int* in_sizes, int n_in,
                              void* d_out, int out_size, void* d_ws, size_t ws_size,
                              hipStream_t stream) {
    (void)in_sizes; (void)n_in; (void)out_size; (void)ws_size;
    const float* X    = (const float*)d_in[0];   // (16,128,200)
    const float* Wih0 = (const float*)d_in[1];   // (2,1024,200)
    const float* Whh0 = (const float*)d_in[2];   // (2,1024,256)
    const float* bih0 = (const float*)d_in[3];
    const float* bhh0 = (const float*)d_in[4];
    const float* Wih1 = (const float*)d_in[5];   // (2,1024,512)
    const float* Whh1 = (const float*)d_in[6];
    const float* bih1 = (const float*)d_in[7];
    const float* bhh1 = (const float*)d_in[8];
    const float* W1   = (const float*)d_in[9];   // (256,1024)
    const float* b1   = (const float*)d_in[10];
    const float* W2   = (const float*)d_in[11];  // (128,256)
    const float* b2   = (const float*)d_in[12];
    const float* W3   = (const float*)d_in[13];  // (1,128)
    const float* b3   = (const float*)d_in[14];
    const int*   tree = (const int*)d_in[15];    // (16,128,2)
    float* out = (float*)d_out;                  // [0]=loss, [1..]=score

    float* ws = (float*)d_ws;
    size_t o = 0;
    float* WihT0 = ws + o; o += (size_t)2 * 200 * 1024;
    float* WihT1 = ws + o; o += (size_t)2 * 512 * 1024;
    float* W1T   = ws + o; o += (size_t)512 * 512;
    float* bsum0 = ws + o; o += 2048;
    float* bsum1 = ws + o; o += 2048;
    float* bhab  = ws + o; o += 512;
    unsigned short* WhhT0 = (unsigned short*)(ws + o); o += (size_t)2 * 256 * 1024 / 2;
    unsigned short* WhhT1 = (unsigned short*)(ws + o); o += (size_t)2 * 256 * 1024 / 2;
    float* xg0  = ws + o; o += (size_t)2 * 2048 * 1024;
    float* xg1  = ws + o; o += (size_t)2 * 2048 * 1024;
    float* emb0 = ws + o; o += (size_t)2048 * 512;
    float* emb1 = ws + o; o += (size_t)2048 * 512;
    float* HaHb = ws + o; o += (size_t)2048 * 512;
    float* res  = ws + o; o += 2048;

    // prep
    k_transpose_N1024<<<dim3(800, 1, 2), 256, 0, stream>>>(Wih0, WihT0, 200);
    k_transpose_N1024<<<dim3(2048, 1, 2), 256, 0, stream>>>(Wih1, WihT1, 512);
    k_whh_bf16<<<dim3(1024, 1, 2), 256, 0, stream>>>(Whh0, WhhT0);
    k_whh_bf16<<<dim3(1024, 1, 2), 256, 0, stream>>>(Whh1, WhhT1);
    k_w1t<<<1024, 256, 0, stream>>>(W1, W1T);
    k_bias<<<18, 256, 0, stream>>>(bih0, bhh0, bih1, bhh1, b1, bsum0, bsum1, bhab);

    // layer 0
    k_gemm<<<dim3(4, 128, 2), 256, 0, stream>>>(X, WihT0, bsum0, xg0, 2048, 200, 1024);
    k_lstm<<<32, 512, 0, stream>>>(xg0, WhhT0, emb0);
    // layer 1
    k_gemm<<<dim3(4, 128, 2), 256, 0, stream>>>(emb0, WihT1, bsum1, xg1, 2048, 512, 1024);
    k_lstm<<<32, 512, 0, stream>>>(xg1, WhhT1, emb1);
    // Ha|Hb
    k_gemm<<<dim3(2, 128, 1), 256, 0, stream>>>(emb1, W1T, bhab, HaHb, 2048, 512, 512);
    // scorer -> out+1
    k_scorer<<<dim3(4, 128, 16), 256, 0, stream>>>(HaHb, W2, b2, W3, b3, out + 1);
    // loss
    k_loss1<<<dim3(127, 16), 128, 0, stream>>>(out + 1, tree, res);
    k_loss2<<<1, 256, 0, stream>>>(res, out);
}

// Round 2
// 1704.580 us; speedup vs baseline: 1.4708x; 1.4708x over previous
//
#include <hip/hip_runtime.h>
#include <hip/hip_bf16.h>
#include <cstdint>
#include <cstddef>

// B=16, S=128, IN=200, H=256, 4H=1024, 2H=512

typedef __attribute__((ext_vector_type(8))) short bf16x8;
typedef __attribute__((ext_vector_type(4))) float f32x4;

__device__ __forceinline__ float bf2f(unsigned short u) {
    return __uint_as_float(((unsigned)u) << 16);
}
__device__ __forceinline__ unsigned short f2bf(float f) {
    unsigned u = __float_as_uint(f);
    u = (u + 0x7FFFu + ((u >> 16) & 1u)) >> 16;
    return (unsigned short)u;
}

// ---------------- prep kernels ----------------

// dst[z][k][n] = src[z][n][k], n<1024, k<K
__global__ void k_transpose_N1024(const float* __restrict__ src, float* __restrict__ dst, int K) {
    int z = blockIdx.z;
    int idx = blockIdx.x * 256 + threadIdx.x;
    if (idx >= K * 1024) return;
    int k = idx >> 10, n = idx & 1023;
    dst[(size_t)z * K * 1024 + idx] = src[(size_t)z * 1024 * K + (size_t)n * K + k];
}

// Whh (2,1024,256) fp32 -> A-fragment layout bf16:
// Wfrag[((d*16+w)*8+ks)*4+t][l][e] = bf16(Whh[d][(r&3)*256 + w*16 + t*4 + (r>>2)][ks*32+(l>>4)*8+e]), r=l&15
__global__ void k_wfrag(const float* __restrict__ Whh, unsigned short* __restrict__ Wfrag) {
    int idx = blockIdx.x * 256 + threadIdx.x;   // 65536 total
    int l = idx & 63;
    int t = (idx >> 6) & 3;
    int ks = (idx >> 8) & 7;
    int w = (idx >> 11) & 15;
    int d = idx >> 15;
    int r = l & 15;
    int kbase = ks * 32 + (l >> 4) * 8;
    int row = (r & 3) * 256 + w * 16 + t * 4 + (r >> 2);
    const float* src = Whh + (size_t)d * (1024 * 256) + (size_t)row * 256 + kbase;
    unsigned short* dst = Wfrag + (size_t)idx * 8;
#pragma unroll
    for (int e = 0; e < 8; ++e) dst[e] = f2bf(src[e]);
}

// W1 (256,1024) -> dst[k][o], k<512, o<512
__global__ void k_w1t(const float* __restrict__ W1, float* __restrict__ dst) {
    int idx = blockIdx.x * 256 + threadIdx.x;
    if (idx >= 512 * 512) return;
    int k = idx >> 9, o = idx & 511;
    dst[idx] = (o < 256) ? W1[(size_t)o * 1024 + k] : W1[(size_t)(o - 256) * 1024 + 512 + k];
}

__global__ void k_bias(const float* __restrict__ bih0, const float* __restrict__ bhh0,
                       const float* __restrict__ bih1, const float* __restrict__ bhh1,
                       const float* __restrict__ b1,
                       float* __restrict__ bsum0, float* __restrict__ bsum1, float* __restrict__ bhab) {
    int idx = blockIdx.x * 256 + threadIdx.x;
    if (idx < 2048) bsum0[idx] = bih0[idx] + bhh0[idx];
    else if (idx < 4096) { int i = idx - 2048; bsum1[i] = bih1[i] + bhh1[i]; }
    else if (idx < 4608) { int i = idx - 4096; bhab[i] = (i < 256) ? b1[i] : 0.f; }
}

// xg[d][b*128+t][n] -> xgfrag: float at d*2097152 + (t*4096 + (j>>4)*256 + ((j>>2)&3)*64 + (j&3)*16 + b)*4 + q
// where n = q*256 + j
__global__ __launch_bounds__(256) void k_reorder(const float* __restrict__ xg, float* __restrict__ xgf) {
    int idx = blockIdx.x * 256 + threadIdx.x;   // 1048576 total
    int n4 = idx & 255;
    int m = (idx >> 8) & 2047;
    int d = idx >> 19;
    int n0 = n4 * 4;
    int q = n0 >> 8;
    int jbase = n0 & 255;
    int b = m >> 7, t = m & 127;
    float4 v = *(const float4*)(xg + ((size_t)(d * 2048 + m)) * 1024 + n0);
    float* base = xgf + (size_t)d * 2097152;
    float vv[4] = {v.x, v.y, v.z, v.w};
#pragma unroll
    for (int dj = 0; dj < 4; ++dj) {
        int j = jbase + dj;
        int fi = (t * 4096 + (j >> 4) * 256 + ((j >> 2) & 3) * 64 + dj * 16 + b) * 4 + q;
        base[fi] = vv[dj];
    }
}

// ---------------- generic GEMM: out[z][m][n] = bias[z][n] + sum_k A[m][k]*Wt[z][k][n] ----------------
template<typename AT>
__global__ __launch_bounds__(256) void k_gemm(
    const AT* __restrict__ A, const float* __restrict__ Wt,
    const float* __restrict__ bias, float* __restrict__ out,
    int M, int K, int N)
{
    int z = blockIdx.z;
    const float* Wtz = Wt + (size_t)z * K * N;
    float* outz = out + (size_t)z * M * N;
    const float* biasz = bias + (size_t)z * N;

    __shared__ float As[16 * 512];
    int tid = threadIdx.x;
    int mq = tid >> 6;
    int nq = tid & 63;
    int n0 = blockIdx.x * 256 + nq * 4;
    int mbase = blockIdx.y * 16;

    for (int r = 0; r < 16; ++r) {
        const AT* Ar = A + (size_t)(mbase + r) * K;
        for (int c = tid; c < K; c += 256) {
            if constexpr (sizeof(AT) == 2) As[r * K + c] = bf2f((unsigned short)Ar[c]);
            else As[r * K + c] = (float)Ar[c];
        }
    }
    __syncthreads();

    float4 bv = *(const float4*)(biasz + n0);
    float acc[4][4];
#pragma unroll
    for (int mi = 0; mi < 4; mi++) { acc[mi][0] = bv.x; acc[mi][1] = bv.y; acc[mi][2] = bv.z; acc[mi][3] = bv.w; }

    const float* asr = As + (mq * 4) * K;
    for (int k = 0; k < K; ++k) {
        float4 w = *(const float4*)(Wtz + (size_t)k * N + n0);
        float x0 = asr[k];
        float x1 = asr[K + k];
        float x2 = asr[2 * K + k];
        float x3 = asr[3 * K + k];
        acc[0][0] += x0 * w.x; acc[0][1] += x0 * w.y; acc[0][2] += x0 * w.z; acc[0][3] += x0 * w.w;
        acc[1][0] += x1 * w.x; acc[1][1] += x1 * w.y; acc[1][2] += x1 * w.z; acc[1][3] += x1 * w.w;
        acc[2][0] += x2 * w.x; acc[2][1] += x2 * w.y; acc[2][2] += x2 * w.z; acc[2][3] += x2 * w.w;
        acc[3][0] += x3 * w.x; acc[3][1] += x3 * w.y; acc[3][2] += x3 * w.z; acc[3][3] += x3 * w.w;
    }
#pragma unroll
    for (int mi = 0; mi < 4; mi++) {
        size_t m = (size_t)mbase + mq * 4 + mi;
        *(float4*)(outz + m * N + n0) = make_float4(acc[mi][0], acc[mi][1], acc[mi][2], acc[mi][3]);
    }
}

// ---------------- MFMA LSTM recurrence: one block per direction ----------------
#define GATE(A, C, H) { \
    float gi = A[0], gf = A[1], gg = A[2], go = A[3]; \
    float si = __builtin_amdgcn_rcpf(1.f + __expf(-gi)); \
    float sf = __builtin_amdgcn_rcpf(1.f + __expf(-gf)); \
    float so = __builtin_amdgcn_rcpf(1.f + __expf(-go)); \
    float eg = __expf(2.f * gg); \
    float tg = 1.f - 2.f * __builtin_amdgcn_rcpf(eg + 1.f); \
    C = sf * C + si * tg; \
    float ec = __expf(2.f * C); \
    float tc = 1.f - 2.f * __builtin_amdgcn_rcpf(ec + 1.f); \
    H = so * tc; }

__global__ __launch_bounds__(1024) void k_lstm_mfma(
    const float* __restrict__ xgf,            // [2][128][16][4][64][4]
    const unsigned short* __restrict__ Wfrag, // [2][16][8][4][64][8] bf16
    unsigned short* __restrict__ emb)         // [2048][512] bf16; this dir writes cols d*256..
{
    const int d = blockIdx.x;
    const int tid = threadIdx.x;
    const int w = tid >> 6;
    const int l = tid & 63;
    const int b = l & 15;
    const int jh = l >> 4;

    __shared__ unsigned short Wlds[8 * 16 * 64 * 8];  // 128 KiB: slots (ks2*4+t)
    __shared__ unsigned short hB[32 * 16 * 8];        // 8 KiB: [kblk][b][e]

    // register-resident weights ks=0..5
    const unsigned short* wgp = Wfrag + ((size_t)(d * 16 + w)) * (8 * 4 * 64 * 8);
    bf16x8 Wr[6][4];
#pragma unroll
    for (int ks = 0; ks < 6; ++ks)
#pragma unroll
        for (int t4 = 0; t4 < 4; ++t4)
            Wr[ks][t4] = *(const bf16x8*)(wgp + ((ks * 4 + t4) * 64 + l) * 8);
    // LDS-resident weights ks=6,7
#pragma unroll
    for (int ks2 = 0; ks2 < 2; ++ks2)
#pragma unroll
        for (int t4 = 0; t4 < 4; ++t4) {
            bf16x8 v = *(const bf16x8*)(wgp + (((6 + ks2) * 4 + t4) * 64 + l) * 8);
            *(bf16x8*)(&Wlds[(ks2 * 4 + t4) * 8192 + w * 512 + l * 8]) = v;
        }
    // zero h state
    *(uint2*)(&hB[tid * 4]) = make_uint2(0u, 0u);

    const int sgn = d ? -1 : 1;
    int t = d ? 127 : 0;
    const f32x4* xb = (const f32x4*)(xgf) + (size_t)d * 524288;
    const int xo = w * 256 + l;

    f32x4 a0 = xb[t * 4096 + xo];
    f32x4 a1 = xb[t * 4096 + xo + 64];
    f32x4 a2 = xb[t * 4096 + xo + 128];
    f32x4 a3 = xb[t * 4096 + xo + 192];

    float c0 = 0.f, c1 = 0.f, c2 = 0.f, c3 = 0.f;
    const int hoff = jh * 128 + b * 8;     // + ks*512
    const int wloff = w * 512 + l * 8;     // + slot*8192
    const int hwoff = w * 256 + b * 8 + jh;
    __syncthreads();

    for (int s = 0; s < 128; ++s) {
#pragma unroll
        for (int ks = 0; ks < 6; ++ks) {
            bf16x8 hf = *(const bf16x8*)(&hB[ks * 512 + hoff]);
            a0 = __builtin_amdgcn_mfma_f32_16x16x32_bf16(Wr[ks][0], hf, a0, 0, 0, 0);
            a1 = __builtin_amdgcn_mfma_f32_16x16x32_bf16(Wr[ks][1], hf, a1, 0, 0, 0);
            a2 = __builtin_amdgcn_mfma_f32_16x16x32_bf16(Wr[ks][2], hf, a2, 0, 0, 0);
            a3 = __builtin_amdgcn_mfma_f32_16x16x32_bf16(Wr[ks][3], hf, a3, 0, 0, 0);
        }
        {
            bf16x8 hf = *(const bf16x8*)(&hB[6 * 512 + hoff]);
            bf16x8 w0 = *(const bf16x8*)(&Wlds[0 * 8192 + wloff]);
            bf16x8 w1 = *(const bf16x8*)(&Wlds[1 * 8192 + wloff]);
            bf16x8 w2 = *(const bf16x8*)(&Wlds[2 * 8192 + wloff]);
            bf16x8 w3 = *(const bf16x8*)(&Wlds[3 * 8192 + wloff]);
            a0 = __builtin_amdgcn_mfma_f32_16x16x32_bf16(w0, hf, a0, 0, 0, 0);
            a1 = __builtin_amdgcn_mfma_f32_16x16x32_bf16(w1, hf, a1, 0, 0, 0);
            a2 = __builtin_amdgcn_mfma_f32_16x16x32_bf16(w2, hf, a2, 0, 0, 0);
            a3 = __builtin_amdgcn_mfma_f32_16x16x32_bf16(w3, hf, a3, 0, 0, 0);
        }
        {
            bf16x8 hf = *(const bf16x8*)(&hB[7 * 512 + hoff]);
            bf16x8 w0 = *(const bf16x8*)(&Wlds[4 * 8192 + wloff]);
            bf16x8 w1 = *(const bf16x8*)(&Wlds[5 * 8192 + wloff]);
            bf16x8 w2 = *(const bf16x8*)(&Wlds[6 * 8192 + wloff]);
            bf16x8 w3 = *(const bf16x8*)(&Wlds[7 * 8192 + wloff]);
            a0 = __builtin_amdgcn_mfma_f32_16x16x32_bf16(w0, hf, a0, 0, 0, 0);
            a1 = __builtin_amdgcn_mfma_f32_16x16x32_bf16(w1, hf, a1, 0, 0, 0);
            a2 = __builtin_amdgcn_mfma_f32_16x16x32_bf16(w2, hf, a2, 0, 0, 0);
            a3 = __builtin_amdgcn_mfma_f32_16x16x32_bf16(w3, hf, a3, 0, 0, 0);
        }
        // gate nonlinearity (acc includes xg + biases via C-init)
        float h0, h1, h2, h3;
        GATE(a0, c0, h0);
        GATE(a1, c1, h1);
        GATE(a2, c2, h2);
        GATE(a3, c3, h3);
        unsigned short u0 = f2bf(h0), u1 = f2bf(h1), u2 = f2bf(h2), u3 = f2bf(h3);
        // emb global write (j = w*16 + t4*4 + jh)
        {
            int ebase = (b * 128 + t) * 512 + d * 256 + w * 16 + jh;
            emb[ebase] = u0;
            emb[ebase + 4] = u1;
            emb[ebase + 8] = u2;
            emb[ebase + 12] = u3;
        }
        // prefetch next step's xg into acc (drained by the barrier)
        int tn = (s == 127) ? t : (t + sgn);
        a0 = xb[tn * 4096 + xo];
        a1 = xb[tn * 4096 + xo + 64];
        a2 = xb[tn * 4096 + xo + 128];
        a3 = xb[tn * 4096 + xo + 192];
        __syncthreads();   // all reads of h_{s-1} complete
        hB[hwoff] = u0;
        hB[hwoff + 4] = u1;
        hB[hwoff + 128] = u2;
        hB[hwoff + 132] = u3;
        __syncthreads();   // h_s visible
        t = tn;
    }
}

// ---------------- fused pairwise scorer ----------------
__global__ __launch_bounds__(256) void k_scorer(
    const float* __restrict__ HaHb, const float* __restrict__ W2,
    const float* __restrict__ b2, const float* __restrict__ W3,
    const float* __restrict__ b3v, float* __restrict__ score)
{
    int jt = blockIdx.x;
    int i  = blockIdx.y;
    int b  = blockIdx.z;
    int tid = threadIdx.x;

    __shared__ __align__(16) float ha[256];
    __shared__ __align__(16) float h1[32 * 260];
    __shared__ __align__(16) float w2s[128 * 36];

    ha[tid] = HaHb[(size_t)(b * 128 + i) * 512 + tid];
    __syncthreads();

    {
        int j = tid >> 3;
        int q = tid & 7;
        const float* hbrow = HaHb + (size_t)(b * 128 + jt * 32 + j) * 512 + 256;
        float* h1r = h1 + j * 260;
#pragma unroll
        for (int cc = 0; cc < 32; ++cc) {
            int c = q + cc * 8;
            float v = ha[c] + hbrow[c];
            h1r[c] = v > 0.f ? v : 0.f;
        }
    }

    float acc[4][4] = {};
    int jq = tid >> 5;
    int rq = tid & 31;

    for (int ch = 0; ch < 8; ++ch) {
        int cb = ch * 32;
        __syncthreads();
        for (int idx = tid; idx < 128 * 32; idx += 256) {
            int r = idx >> 5, cc = idx & 31;
            w2s[r * 36 + cc] = W2[(size_t)r * 256 + cb + cc];
        }
        __syncthreads();
#pragma unroll
        for (int cc = 0; cc < 32; cc += 4) {
            float4 hv[4], wv[4];
#pragma unroll
            for (int jj = 0; jj < 4; ++jj)
                hv[jj] = *(const float4*)(h1 + (jq + jj * 8) * 260 + cb + cc);
#pragma unroll
            for (int rr = 0; rr < 4; ++rr)
                wv[rr] = *(const float4*)(w2s + (rq + rr * 32) * 36 + cc);
#pragma unroll
            for (int jj = 0; jj < 4; ++jj)
#pragma unroll
                for (int rr = 0; rr < 4; ++rr)
                    acc[jj][rr] += hv[jj].x * wv[rr].x + hv[jj].y * wv[rr].y +
                                   hv[jj].z * wv[rr].z + hv[jj].w * wv[rr].w;
        }
    }

    float part0 = 0.f, part1 = 0.f, part2 = 0.f, part3 = 0.f;
#pragma unroll
    for (int rr = 0; rr < 4; ++rr) {
        int r = rq + rr * 32;
        float bb = b2[r], ww = W3[r];
        float t0 = acc[0][rr] + bb; if (t0 > 0.f) part0 += t0 * ww;
        float t1 = acc[1][rr] + bb; if (t1 > 0.f) part1 += t1 * ww;
        float t2 = acc[2][rr] + bb; if (t2 > 0.f) part2 += t2 * ww;
        float t3 = acc[3][rr] + bb; if (t3 > 0.f) part3 += t3 * ww;
    }
#pragma unroll
    for (int off = 16; off >= 1; off >>= 1) {
        part0 += __shfl_xor(part0, off, 32);
        part1 += __shfl_xor(part1, off, 32);
        part2 += __shfl_xor(part2, off, 32);
        part3 += __shfl_xor(part3, off, 32);
    }
    if (rq == 0) {
        float bb3 = b3v[0];
        float p[4] = {part0, part1, part2, part3};
#pragma unroll
        for (int jj = 0; jj < 4; ++jj) {
            int jg = jt * 32 + jq + jj * 8;
            float sc = p[jj] + bb3;
            sc = sc > 0.f ? sc : 0.f;
            if (jg == i || jg == 0) sc = 0.f;
            score[(size_t)(b * 128 + i) * 128 + jg] = sc;
        }
    }
}

// ---------------- loss ----------------
__global__ __launch_bounds__(128) void k_loss1(
    const float* __restrict__ score, const int* __restrict__ tree, float* __restrict__ res)
{
    int k = blockIdx.x;
    int b = blockIdx.y;
    int head = tree[((size_t)b * 128 + k + 1) * 2 + 0];
    int dep  = tree[((size_t)b * 128 + k + 1) * 2 + 1];
    int i = threadIdx.x;
    float s = score[((size_t)b * 128 + i) * 128 + dep];
    float v = (i == dep) ? 0.f : __expf(s);
    __shared__ float redu[2];
#pragma unroll
    for (int off = 32; off >= 1; off >>= 1) v += __shfl_down(v, off, 64);
    if ((i & 63) == 0) redu[i >> 6] = v;
    __syncthreads();
    if (i == 0) {
        float norm = redu[0] + redu[1];
        float num = score[((size_t)b * 128 + head) * 128 + dep];
        res[b * 127 + k] = __logf(norm) - num;
    }
}

__global__ __launch_bounds__(256) void k_loss2(const float* __restrict__ res, float* __restrict__ out) {
    int tid = threadIdx.x;
    float a = 0.f;
    for (int idx = tid; idx < 16 * 127; idx += 256) a += res[idx];
    __shared__ float sm[256];
    sm[tid] = a;
    __syncthreads();
    for (int off = 128; off >= 1; off >>= 1) {
        if (tid < off) sm[tid] += sm[tid + off];
        __syncthreads();
    }
    if (tid == 0) out[0] = sm[0] / 127.f;
}

// ---------------- host launcher ----------------
extern "C" void kernel_launch(void* const* d_in, const int* in_sizes, int n_in,
                              void* d_out, int out_size, void* d_ws, size_t ws_size,
                              hipStream_t stream) {
    (void)in_sizes; (void)n_in; (void)out_size; (void)ws_size;
    const float* X    = (const float*)d_in[0];
    const float* Wih0 = (const float*)d_in[1];
    const float* Whh0 = (const float*)d_in[2];
    const float* bih0 = (const float*)d_in[3];
    const float* bhh0 = (const float*)d_in[4];
    const float* Wih1 = (const float*)d_in[5];
    const float* Whh1 = (const float*)d_in[6];
    const float* bih1 = (const float*)d_in[7];
    const float* bhh1 = (const float*)d_in[8];
    const float* W1   = (const float*)d_in[9];
    const float* b1   = (const float*)d_in[10];
    const float* W2   = (const float*)d_in[11];
    const float* b2   = (const float*)d_in[12];
    const float* W3   = (const float*)d_in[13];
    const float* b3   = (const float*)d_in[14];
    const int*   tree = (const int*)d_in[15];
    float* out = (float*)d_out;   // [0]=loss, [1..]=score

    float* ws = (float*)d_ws;
    size_t o = 0;
    float* WihT0 = ws + o; o += (size_t)2 * 200 * 1024;
    float* WihT1 = ws + o; o += (size_t)2 * 512 * 1024;
    float* W1T   = ws + o; o += (size_t)512 * 512;
    float* bsum0 = ws + o; o += 2048;
    float* bsum1 = ws + o; o += 2048;
    float* bhab  = ws + o; o += 512;
    unsigned short* Wf0 = (unsigned short*)(ws + o); o += (size_t)2 * 16 * 8 * 4 * 64 * 8 / 2;
    unsigned short* Wf1 = (unsigned short*)(ws + o); o += (size_t)2 * 16 * 8 * 4 * 64 * 8 / 2;
    float* xg   = ws + o; o += (size_t)2 * 2048 * 1024;   // shared between layers
    float* xgf  = ws + o; o += (size_t)2 * 2048 * 1024;   // shared between layers
    unsigned short* emb0 = (unsigned short*)(ws + o); o += (size_t)2048 * 512 / 2;
    unsigned short* emb1 = (unsigned short*)(ws + o); o += (size_t)2048 * 512 / 2;
    float* HaHb = ws + o; o += (size_t)2048 * 512;
    float* res  = ws + o; o += 2048;

    // prep
    k_transpose_N1024<<<dim3(800, 1, 2), 256, 0, stream>>>(Wih0, WihT0, 200);
    k_transpose_N1024<<<dim3(2048, 1, 2), 256, 0, stream>>>(Wih1, WihT1, 512);
    k_wfrag<<<256, 256, 0, stream>>>(Whh0, Wf0);
    k_wfrag<<<256, 256, 0, stream>>>(Whh1, Wf1);
    k_w1t<<<1024, 256, 0, stream>>>(W1, W1T);
    k_bias<<<18, 256, 0, stream>>>(bih0, bhh0, bih1, bhh1, b1, bsum0, bsum1, bhab);

    // layer 0
    k_gemm<float><<<dim3(4, 128, 2), 256, 0, stream>>>(X, WihT0, bsum0, xg, 2048, 200, 1024);
    k_reorder<<<4096, 256, 0, stream>>>(xg, xgf);
    k_lstm_mfma<<<2, 1024, 0, stream>>>(xgf, Wf0, emb0);
    // layer 1
    k_gemm<unsigned short><<<dim3(4, 128, 2), 256, 0, stream>>>(emb0, WihT1, bsum1, xg, 2048, 512, 1024);
    k_reorder<<<4096, 256, 0, stream>>>(xg, xgf);
    k_lstm_mfma<<<2, 1024, 0, stream>>>(xgf, Wf1, emb1);
    // Ha|Hb
    k_gemm<unsigned short><<<dim3(2, 128, 1), 256, 0, stream>>>(emb1, W1T, bhab, HaHb, 2048, 512, 512);
    // scorer -> out+1
    k_scorer<<<dim3(4, 128, 16), 256, 0, stream>>>(HaHb, W2, b2, W3, b3, out + 1);
    // loss
    k_loss1<<<dim3(127, 16), 128, 0, stream>>>(out + 1, tree, res);
    k_loss2<<<1, 256, 0, stream>>>(res, out);
}